// Round 16
// baseline (1128.172 us; speedup 1.0000x reference)
//
#include <hip/hip_runtime.h>

// ---------------------------------------------------------------------------
// Child-Sum TreeLSTM, complete binary tree, level-wise bottom-up, bf16 MFMA.
// Round 16: 8 waves/SIMD WITHOUT spill.
//   R15 lesson: unified VGPR+AGPR budget must be <=64 for 8 waves/SIMD; the
//   6-plane merged body (~84 total) spilled. Fix: interior = TWO 3-plane
//   passes: A {xf,f1h,fs} -> fold cvf = f1*c1+f2*c2 -> B {ai,ao,au}.
//   Peak ~60 total regs. Cost: ax/ah re-read per tile (L2-served, HBM idle).
//   Interior: 1024-thr blocks (16 waves) x 64KB LDS -> 2 blocks/CU = 32 w/CU.
//   Leaf: 512-thr x 24KB -> 4 blocks/CU, grid 1024 = 32 w/CU (already 3-plane).
// Tripwire: big-dispatch WRITE_SIZE ~1.5e5 KB; >2.5e5 = spill, revert.
//
// mfma_f32_16x16x32_bf16: A lane: row=l&15, k=(l>>4)*8+e  (16B/lane)
//                         B lane: col=l&15, k=(l>>4)*8+e = W[col][k]
//                         D: col=l&15, row=(l>>4)*4+r, r=0..3
// ---------------------------------------------------------------------------

typedef __attribute__((ext_vector_type(8))) short bf16x8;
typedef __attribute__((ext_vector_type(8))) unsigned short us8;
typedef __attribute__((ext_vector_type(4))) float f32x4;
typedef __attribute__((ext_vector_type(4))) float f4;

#define MFMA16(A, B, C) __builtin_amdgcn_mfma_f32_16x16x32_bf16(A, B, C, 0, 0, 0)

__device__ __forceinline__ unsigned short f2b(float f) {
  unsigned int u = __builtin_bit_cast(unsigned int, f);
  u = u + 0x7FFFu + ((u >> 16) & 1u);   // RNE
  return (unsigned short)(u >> 16);
}
__device__ __forceinline__ float bf2f(unsigned short u) {
  unsigned int v = (unsigned int)u << 16;
  return __builtin_bit_cast(float, v);
}
__device__ __forceinline__ us8 pack8(f4 a, f4 b) {
  us8 r;
  r[0] = f2b(a[0]); r[1] = f2b(a[1]); r[2] = f2b(a[2]); r[3] = f2b(a[3]);
  r[4] = f2b(b[0]); r[5] = f2b(b[1]); r[6] = f2b(b[2]); r[7] = f2b(b[3]);
  return r;
}
__device__ __forceinline__ float sigm(float x) { return 1.0f / (1.0f + __expf(-x)); }
__device__ __forceinline__ float tanh_f(float x) { return 2.0f / (1.0f + __expf(-2.0f * x)) - 1.0f; }

__global__ void pack_w(const float* __restrict__ a,  // Wioux 768x256
                       const float* __restrict__ b,  // Wiouh 768x256
                       const float* __restrict__ c,  // Wfx   256x256
                       const float* __restrict__ d,  // Wfh   256x256
                       unsigned short* __restrict__ out) {
  int i = blockIdx.x * blockDim.x + threadIdx.x;  // 0 .. 524287
  const int A = 768 * 256;
  const int B = A + 768 * 256;
  const int C = B + 256 * 256;
  float v;
  if (i < A)      v = a[i];
  else if (i < B) v = b[i - A];
  else if (i < C) v = c[i - B];
  else            v = d[i - C];
  out[i] = f2b(v);
}

// convert ALL node x rows to bf16 (8 elems/thread)
__global__ void conv_x(const float* __restrict__ x, unsigned short* __restrict__ xb, int n8) {
  int i = blockIdx.x * blockDim.x + threadIdx.x;
  if (i >= n8) return;
  f4 a = __builtin_nontemporal_load((const f4*)(x + (size_t)i * 8));
  f4 b = __builtin_nontemporal_load((const f4*)(x + (size_t)i * 8 + 4));
  __builtin_nontemporal_store(pack8(a, b), (us8*)(xb + (size_t)i * 8));
}

// LDS planes: 0 Wx_i, 1 Wx_o, 2 Wx_u, 3 Wh_i, 4 Wh_o, 5 Wh_u, 6 Wfx, 7 Wfh
// per plane: [kc8][kg4][col16][e8] -> a wave's b128 read is 1KB contiguous.
template<int LEAF, int TPB>
__global__ __launch_bounds__(TPB) __attribute__((amdgpu_waves_per_eu(8)))
void level_k(
    const unsigned short* __restrict__ xb,     // [N][256] bf16
    const unsigned short* __restrict__ wb,     // packed bf16 weights
    const float* __restrict__ bioux,
    const float* __restrict__ bfx,
    const float* __restrict__ fb,
    float* __restrict__ h_all,                 // d_out + 512
    const unsigned short* __restrict__ hs_r,   // hsum of children, level-local
    const unsigned short* __restrict__ hbe_r,  // h of even child
    const unsigned int* __restrict__ cp_r,     // packed (c_even | c_odd<<16)
    unsigned short* __restrict__ hs_w,         // for parent level
    unsigned short* __restrict__ hbe_w,
    unsigned int* __restrict__ cp_w,
    float* __restrict__ out0,
    int s, int L, int T16, int root, int lns)  // lns: log2(stripe count)
{
  extern __shared__ unsigned short W[];

  const int tid    = threadIdx.x;
  const int NWV    = TPB / 64;
  const int NS     = 1 << lns;
  const int cg     = blockIdx.x >> lns;       // column group (16 cols)
  const int stripe = blockIdx.x & (NS - 1);   // XCD = stripe % 8

  // ---- stage weights for this cg into LDS (once) ----
  const int NP = LEAF ? 3 : 8;
  #pragma unroll 1
  for (int c = tid; c < NP * 512; c += TPB) {
    const int p   = c >> 9;
    const int q   = c & 511;
    const int kc  = q >> 6;
    const int kg  = (q >> 4) & 3;
    const int col = q & 15;
    const int po = (p < 3) ? p * 65536
                 : (p < 6) ? 196608 + (p - 3) * 65536
                 : (p == 6) ? 393216 : 458752;
    us8 v = *(const us8*)(wb + po + (size_t)(cg * 16 + col) * 256 + kc * 32 + kg * 8);
    *(us8*)(W + p * 4096 + ((kc * 4 + kg) * 16 + col) * 8) = v;
  }
  __syncthreads();   // only barrier; waves free-run after

  const int lane = tid & 63;
  const int wv   = tid >> 6;          // 0..NWV-1
  const int lm   = lane & 15;
  const int kgl  = lane >> 4;         // 0..3
  const int colc = cg * 16 + lm;

  const unsigned short* LW = W + kgl * 128 + lm * 8;  // + p*4096 + kc*512

  const float bi_ = bioux[colc];
  const float bo_ = bioux[256 + colc];
  const float bu_ = bioux[512 + colc];
  const float bf_ = LEAF ? 0.f : (bfx[colc] + fb[colc]);

  const int Tper = (T16 + NS - 1) >> lns;
  const int t0   = stripe * Tper;
  const int tE   = (t0 + Tper < T16) ? (t0 + Tper) : T16;

  for (int t = t0 + wv; t < tE; t += NWV) {
    const int tb16  = t * 16;
    const int drow0 = tb16 + kgl * 4;
    const unsigned short* xr = xb + (size_t)(s + tb16 + lm) * 256 + kgl * 8;
    const f32x4 z4 = {0.f, 0.f, 0.f, 0.f};

    if (!LEAF) {
      const unsigned short* hbr = hbe_r + (size_t)(tb16 + lm) * 256 + kgl * 8;
      const unsigned short* hsr = hs_r  + (size_t)(tb16 + lm) * 256 + kgl * 8;

      // c gather issued first: latency hides under pass A
      unsigned int cpv[4];
      #pragma unroll
      for (int r = 0; r < 4; ++r)
        cpv[r] = cp_r[(size_t)(drow0 + r) * 256 + colc];

      // ---- pass A: xf = x@Wfx, f1h = h1@Wfh, fs = hsum@Wfh (3 planes) ----
      f32x4 xf = z4, f1h = z4, fs = z4;
      #pragma unroll 2
      for (int kc = 0; kc < 8; ++kc) {
        bf16x8 ax = *(const bf16x8*)(xr  + kc * 32);
        bf16x8 a1 = *(const bf16x8*)(hbr + kc * 32);
        bf16x8 ah = *(const bf16x8*)(hsr + kc * 32);
        bf16x8 b6 = *(const bf16x8*)(LW + 6 * 4096 + kc * 512);
        bf16x8 b7 = *(const bf16x8*)(LW + 7 * 4096 + kc * 512);
        xf  = MFMA16(ax, b6, xf);
        f1h = MFMA16(a1, b7, f1h);
        fs  = MFMA16(ah, b7, fs);
      }

      // fold forget gates -> cvf (frees all 3 pass-A planes)
      float cvf[4];
      #pragma unroll
      for (int r = 0; r < 4; ++r) {
        const float f1 = sigm(xf[r] + f1h[r] + bf_);
        const float f2 = sigm(xf[r] + fs[r] - f1h[r] + bf_);  // h2@W = hs@W - h1@W
        const float c1 = bf2f((unsigned short)(cpv[r] & 0xffffu));
        const float c2 = bf2f((unsigned short)(cpv[r] >> 16));
        cvf[r] = f1 * c1 + f2 * c2;
      }

      // ---- pass B: ai,ao,au = x@Wx + hsum@Wh (3 planes) ----
      f32x4 ai = z4, ao = z4, au = z4;
      #pragma unroll 2
      for (int kc = 0; kc < 8; ++kc) {
        bf16x8 ax = *(const bf16x8*)(xr  + kc * 32);
        bf16x8 ah = *(const bf16x8*)(hsr + kc * 32);
        bf16x8 b0 = *(const bf16x8*)(LW + 0 * 4096 + kc * 512);
        bf16x8 b1 = *(const bf16x8*)(LW + 1 * 4096 + kc * 512);
        bf16x8 b2 = *(const bf16x8*)(LW + 2 * 4096 + kc * 512);
        bf16x8 b3 = *(const bf16x8*)(LW + 3 * 4096 + kc * 512);
        bf16x8 b4 = *(const bf16x8*)(LW + 4 * 4096 + kc * 512);
        bf16x8 b5 = *(const bf16x8*)(LW + 5 * 4096 + kc * 512);
        ai = MFMA16(ax, b0, ai);
        ao = MFMA16(ax, b1, ao);
        au = MFMA16(ax, b2, au);
        ai = MFMA16(ah, b3, ai);
        ao = MFMA16(ah, b4, ao);
        au = MFMA16(ah, b5, au);
      }

      // ---- epilogue ----
      float hv4[4], cv4[4];
      #pragma unroll
      for (int r = 0; r < 4; ++r) {
        const float i_ = sigm(ai[r] + bi_);
        const float u_ = tanh_f(au[r] + bu_);
        const float o_ = sigm(ao[r] + bo_);
        const float c_ = i_ * u_ + cvf[r];
        const float h_ = o_ * tanh_f(c_);
        cv4[r] = c_; hv4[r] = h_;
        const int j = drow0 + r;
        if (j < L)
          __builtin_nontemporal_store(h_, h_all + (size_t)(s + j) * 256 + colc);
      }
      if (root) {
        if (drow0 == 0) { out0[colc] = hv4[0]; out0[256 + colc] = cv4[0]; }
      } else {
        #pragma unroll
        for (int rp = 0; rp < 2; ++rp) {
          const int j0 = drow0 + rp * 2;
          if (j0 + 1 < L) {
            const int pp = j0 >> 1;
            hs_w [(size_t)pp * 256 + colc] = f2b(hv4[rp*2] + hv4[rp*2+1]);
            hbe_w[(size_t)pp * 256 + colc] = f2b(hv4[rp*2]);
            cp_w [(size_t)pp * 256 + colc] =
                (unsigned int)f2b(cv4[rp*2]) | ((unsigned int)f2b(cv4[rp*2+1]) << 16);
          }
        }
      }
    } else {
      // ---- leaf: i,o,u from x only (3 planes, fits 64-reg budget) ----
      f32x4 ai = z4, ao = z4, au = z4;
      #pragma unroll 2
      for (int kc = 0; kc < 8; ++kc) {
        bf16x8 ax = *(const bf16x8*)(xr + kc * 32);
        bf16x8 b0 = *(const bf16x8*)(LW + 0 * 4096 + kc * 512);
        bf16x8 b1 = *(const bf16x8*)(LW + 1 * 4096 + kc * 512);
        bf16x8 b2 = *(const bf16x8*)(LW + 2 * 4096 + kc * 512);
        ai = MFMA16(ax, b0, ai);
        ao = MFMA16(ax, b1, ao);
        au = MFMA16(ax, b2, au);
      }
      float hv4[4], cv4[4];
      #pragma unroll
      for (int r = 0; r < 4; ++r) {
        const float i_ = sigm(ai[r] + bi_);
        const float u_ = tanh_f(au[r] + bu_);
        const float o_ = sigm(ao[r] + bo_);
        const float c_ = i_ * u_;
        const float h_ = o_ * tanh_f(c_);
        cv4[r] = c_; hv4[r] = h_;
        __builtin_nontemporal_store(h_, h_all + (size_t)(s + drow0 + r) * 256 + colc);
      }
      #pragma unroll
      for (int rp = 0; rp < 2; ++rp) {
        const int pp = (drow0 + rp * 2) >> 1;
        hs_w [(size_t)pp * 256 + colc] = f2b(hv4[rp*2] + hv4[rp*2+1]);
        hbe_w[(size_t)pp * 256 + colc] = f2b(hv4[rp*2]);
        cp_w [(size_t)pp * 256 + colc] =
            (unsigned int)f2b(cv4[rp*2]) | ((unsigned int)f2b(cv4[rp*2+1]) << 16);
      }
    }
  }
}

extern "C" void kernel_launch(void* const* d_in, const int* in_sizes, int n_in,
                              void* d_out, int out_size, void* d_ws, size_t ws_size,
                              hipStream_t stream) {
  const float* inputs = (const float*)d_in[0];
  const float* Wioux  = (const float*)d_in[1];
  const float* bioux  = (const float*)d_in[2];
  const float* Wiouh  = (const float*)d_in[3];
  const float* Wfx    = (const float*)d_in[4];
  const float* bfx    = (const float*)d_in[5];
  const float* Wfh    = (const float*)d_in[6];
  const float* fb     = (const float*)d_in[7];

  const int N = in_sizes[0] / 256;       // 262143
  int depth = 0;
  while (((1 << depth) - 1) < N) ++depth;  // 18

  float* out   = (float*)d_out;
  float* h_all = out + 512;

  static bool attr_done = false;
  if (!attr_done) {
    hipFuncSetAttribute((const void*)level_k<0, 1024>,
                        hipFuncAttributeMaxDynamicSharedMemorySize, 8 * 8192);
    hipFuncSetAttribute((const void*)level_k<1, 512>,
                        hipFuncAttributeMaxDynamicSharedMemorySize, 3 * 8192);
    attr_done = true;
  }

  // ws carve: parity-0 buffers (up to 65536 rows), parity-1 (32768), xb, wb
  char* p = (char*)d_ws;
  unsigned short* hs0  = (unsigned short*)p; p += (size_t)65536 * 256 * 2;
  unsigned short* hbe0 = (unsigned short*)p; p += (size_t)65536 * 256 * 2;
  unsigned int*   cp0  = (unsigned int*)p;   p += (size_t)65536 * 256 * 4;
  unsigned short* hs1  = (unsigned short*)p; p += (size_t)32768 * 256 * 2;
  unsigned short* hbe1 = (unsigned short*)p; p += (size_t)32768 * 256 * 2;
  unsigned int*   cp1  = (unsigned int*)p;   p += (size_t)32768 * 256 * 4;
  unsigned short* xb   = (unsigned short*)p; p += (size_t)N * 256 * 2;
  unsigned short* wb   = (unsigned short*)p;

  pack_w<<<2048, 256, 0, stream>>>(Wioux, Wiouh, Wfx, Wfh, wb);
  {
    const int n8 = (N * 256) / 8;
    conv_x<<<(n8 + 255) / 256, 256, 0, stream>>>(inputs, xb, n8);
  }

  for (int d = depth - 1; d >= 0; --d) {
    const int L = 1 << d;
    const int s = L - 1;
    const int T16 = (L + 15) / 16;
    const int rp_ = d & 1, wp_ = (d - 1) & 1;
    const unsigned short* hs_r  = rp_ ? hs1 : hs0;
    const unsigned short* hbe_r = rp_ ? hbe1 : hbe0;
    const unsigned int*   cp_r  = rp_ ? cp1 : cp0;
    unsigned short* hs_w  = wp_ ? hs1 : hs0;
    unsigned short* hbe_w = wp_ ? hbe1 : hbe0;
    unsigned int*   cp_w  = wp_ ? cp1 : cp0;
    if (d == depth - 1) {
      // leaf: 512-thr, 24KB LDS -> 4 blocks/CU; NS=64 -> grid 1024 = 32 w/CU
      level_k<1, 512><<<1024, 512, 3 * 8192, stream>>>(
          xb, wb, bioux, bfx, fb, h_all,
          hs_r, hbe_r, cp_r, hs_w, hbe_w, cp_w, out, s, L, T16, 0, 6);
    } else {
      // interior: 1024-thr (16 waves), 64KB LDS -> 2 blocks/CU; NS=32 ->
      // grid 512 = 32 waves/CU at <=64 total regs (two-pass 3-plane body)
      level_k<0, 1024><<<512, 1024, 8 * 8192, stream>>>(
          xb, wb, bioux, bfx, fb, h_all,
          hs_r, hbe_r, cp_r, hs_w, hbe_w, cp_w, out, s, L, T16, (d == 0) ? 1 : 0, 5);
    }
  }
}

// Round 17
// 934.560 us; speedup vs baseline: 1.2072x; 1.2072x over previous
//
#include <hip/hip_runtime.h>

// ---------------------------------------------------------------------------
// Child-Sum TreeLSTM, complete binary tree, level-wise bottom-up, bf16 MFMA.
// Round 17 = R13 (the validated anchor: VGPR 60, no spill, 229us/level) with
// 2-subtile B-sharing: each wave processes TWO 16-node subtiles per loop
// iteration, sharing every LDS B-frag read -> per-node LDS-read bytes halve
// (the dominant throughput term), and each B read feeds 2 MFMAs.
// Register budget: 12 acc planes (48) + in-flight frags + addressing ~ 124;
// amdgpu_waves_per_eu(4) pins the cap at 128 (= 4 waves/SIMD, which the
// 64KB weight LDS limits us to anyway). R15/R16 proved 8 waves/SIMD (64-reg
// cap) cannot hold any MFMA body -> stop chasing it.
// Small levels: grid sized by lns = log2(T32)-3 so they don't launch 512
// weight-staging blocks for 32 tiles of work.
// Tripwires (level 16): FETCH ~8.6e4 KB, WRITE ~1.5e5 KB; inflation = spill.
//
// mfma_f32_16x16x32_bf16: A lane: row=l&15, k=(l>>4)*8+e  (16B/lane)
//                         B lane: col=l&15, k=(l>>4)*8+e = W[col][k]
//                         D: col=l&15, row=(l>>4)*4+r, r=0..3
// ---------------------------------------------------------------------------

typedef __attribute__((ext_vector_type(8))) short bf16x8;
typedef __attribute__((ext_vector_type(8))) unsigned short us8;
typedef __attribute__((ext_vector_type(4))) float f32x4;
typedef __attribute__((ext_vector_type(4))) float f4;

#define MFMA16(A, B, C) __builtin_amdgcn_mfma_f32_16x16x32_bf16(A, B, C, 0, 0, 0)

__device__ __forceinline__ unsigned short f2b(float f) {
  unsigned int u = __builtin_bit_cast(unsigned int, f);
  u = u + 0x7FFFu + ((u >> 16) & 1u);   // RNE
  return (unsigned short)(u >> 16);
}
__device__ __forceinline__ float bf2f(unsigned short u) {
  unsigned int v = (unsigned int)u << 16;
  return __builtin_bit_cast(float, v);
}
__device__ __forceinline__ us8 pack8(f4 a, f4 b) {
  us8 r;
  r[0] = f2b(a[0]); r[1] = f2b(a[1]); r[2] = f2b(a[2]); r[3] = f2b(a[3]);
  r[4] = f2b(b[0]); r[5] = f2b(b[1]); r[6] = f2b(b[2]); r[7] = f2b(b[3]);
  return r;
}
__device__ __forceinline__ float sigm(float x) { return 1.0f / (1.0f + __expf(-x)); }
__device__ __forceinline__ float tanh_f(float x) { return 2.0f / (1.0f + __expf(-2.0f * x)) - 1.0f; }

__global__ void pack_w(const float* __restrict__ a,  // Wioux 768x256
                       const float* __restrict__ b,  // Wiouh 768x256
                       const float* __restrict__ c,  // Wfx   256x256
                       const float* __restrict__ d,  // Wfh   256x256
                       unsigned short* __restrict__ out) {
  int i = blockIdx.x * blockDim.x + threadIdx.x;  // 0 .. 524287
  const int A = 768 * 256;
  const int B = A + 768 * 256;
  const int C = B + 256 * 256;
  float v;
  if (i < A)      v = a[i];
  else if (i < B) v = b[i - A];
  else if (i < C) v = c[i - B];
  else            v = d[i - C];
  out[i] = f2b(v);
}

// convert ALL node x rows to bf16 (8 elems/thread)
__global__ void conv_x(const float* __restrict__ x, unsigned short* __restrict__ xb, int n8) {
  int i = blockIdx.x * blockDim.x + threadIdx.x;
  if (i >= n8) return;
  f4 a = __builtin_nontemporal_load((const f4*)(x + (size_t)i * 8));
  f4 b = __builtin_nontemporal_load((const f4*)(x + (size_t)i * 8 + 4));
  __builtin_nontemporal_store(pack8(a, b), (us8*)(xb + (size_t)i * 8));
}

// LDS planes: 0 Wx_i, 1 Wx_o, 2 Wx_u, 3 Wh_i, 4 Wh_o, 5 Wh_u, 6 Wfx, 7 Wfh
// per plane: [kc8][kg4][col16][e8] -> a wave's b128 read is 1KB contiguous.
template<int LEAF>
__global__ __launch_bounds__(512) __attribute__((amdgpu_waves_per_eu(4)))
void level_k(
    const unsigned short* __restrict__ xb,     // [N][256] bf16
    const unsigned short* __restrict__ wb,     // packed bf16 weights
    const float* __restrict__ bioux,
    const float* __restrict__ bfx,
    const float* __restrict__ fb,
    float* __restrict__ h_all,                 // d_out + 512
    const unsigned short* __restrict__ hs_r,   // hsum of children, level-local
    const unsigned short* __restrict__ hbe_r,  // h of even child
    const unsigned int* __restrict__ cp_r,     // packed (c_even | c_odd<<16)
    unsigned short* __restrict__ hs_w,         // for parent level
    unsigned short* __restrict__ hbe_w,
    unsigned int* __restrict__ cp_w,
    float* __restrict__ out0,
    int s, int L, int T32, int root, int lns)  // lns: log2(stripe count)
{
  extern __shared__ unsigned short W[];

  const int tid    = threadIdx.x;
  const int NS     = 1 << lns;
  const int cg     = blockIdx.x >> lns;       // column group (16 cols)
  const int stripe = blockIdx.x & (NS - 1);

  // ---- stage weights for this cg into LDS (once) ----
  const int NP = LEAF ? 3 : 8;
  #pragma unroll 1
  for (int c = tid; c < NP * 512; c += 512) {
    const int p   = c >> 9;
    const int q   = c & 511;
    const int kc  = q >> 6;
    const int kg  = (q >> 4) & 3;
    const int col = q & 15;
    const int po = (p < 3) ? p * 65536
                 : (p < 6) ? 196608 + (p - 3) * 65536
                 : (p == 6) ? 393216 : 458752;
    us8 v = *(const us8*)(wb + po + (size_t)(cg * 16 + col) * 256 + kc * 32 + kg * 8);
    *(us8*)(W + p * 4096 + ((kc * 4 + kg) * 16 + col) * 8) = v;
  }
  __syncthreads();   // only barrier; waves free-run after

  const int lane = tid & 63;
  const int wv   = tid >> 6;          // 0..7
  const int lm   = lane & 15;
  const int kgl  = lane >> 4;         // 0..3
  const int colc = cg * 16 + lm;

  const unsigned short* LW = W + kgl * 128 + lm * 8;  // + p*4096 + kc*512

  const float bi_ = bioux[colc];
  const float bo_ = bioux[256 + colc];
  const float bu_ = bioux[512 + colc];
  const float bf_ = LEAF ? 0.f : (bfx[colc] + fb[colc]);

  const int Tper = (T32 + NS - 1) >> lns;
  const int t0   = stripe * Tper;
  const int tE   = (t0 + Tper < T32) ? (t0 + Tper) : T32;

  for (int t = t0 + wv; t < tE; t += 8) {
    const int tb    = t * 32;                 // 32 nodes per iteration
    const int drowA = tb + kgl * 4;
    const int drowB = tb + 16 + kgl * 4;
    const unsigned short* xr0 = xb + (size_t)(s + tb + lm) * 256 + kgl * 8;
    const unsigned short* xr1 = xr0 + 16 * 256;
    const f32x4 z4 = {0.f, 0.f, 0.f, 0.f};

    if (!LEAF) {
      const unsigned short* hb0 = hbe_r + (size_t)(tb + lm) * 256 + kgl * 8;
      const unsigned short* hb1 = hb0 + 16 * 256;
      const unsigned short* hs0 = hs_r  + (size_t)(tb + lm) * 256 + kgl * 8;
      const unsigned short* hs1 = hs0 + 16 * 256;

      unsigned int cpA[4], cpB[4];
      #pragma unroll
      for (int r = 0; r < 4; ++r) {
        cpA[r] = cp_r[(size_t)(drowA + r) * 256 + colc];
        cpB[r] = cp_r[(size_t)(drowB + r) * 256 + colc];
      }

      // ---- merged K-sweep, 2 subtiles sharing every B-frag ----
      f32x4 xfA = z4, f1A = z4, aiA = z4, aoA = z4, auA = z4, fsA = z4;
      f32x4 xfB = z4, f1B = z4, aiB = z4, aoB = z4, auB = z4, fsB = z4;
      #pragma unroll 2
      for (int kc = 0; kc < 8; ++kc) {
        bf16x8 ax0 = *(const bf16x8*)(xr0 + kc * 32);
        bf16x8 ax1 = *(const bf16x8*)(xr1 + kc * 32);
        bf16x8 a10 = *(const bf16x8*)(hb0 + kc * 32);
        bf16x8 a11 = *(const bf16x8*)(hb1 + kc * 32);
        bf16x8 ah0 = *(const bf16x8*)(hs0 + kc * 32);
        bf16x8 ah1 = *(const bf16x8*)(hs1 + kc * 32);
        bf16x8 b6 = *(const bf16x8*)(LW + 6 * 4096 + kc * 512);
        bf16x8 b7 = *(const bf16x8*)(LW + 7 * 4096 + kc * 512);
        bf16x8 b0 = *(const bf16x8*)(LW + 0 * 4096 + kc * 512);
        bf16x8 b1 = *(const bf16x8*)(LW + 1 * 4096 + kc * 512);
        bf16x8 b2 = *(const bf16x8*)(LW + 2 * 4096 + kc * 512);
        bf16x8 b3 = *(const bf16x8*)(LW + 3 * 4096 + kc * 512);
        bf16x8 b4 = *(const bf16x8*)(LW + 4 * 4096 + kc * 512);
        bf16x8 b5 = *(const bf16x8*)(LW + 5 * 4096 + kc * 512);
        xfA = MFMA16(ax0, b6, xfA);  xfB = MFMA16(ax1, b6, xfB);
        f1A = MFMA16(a10, b7, f1A);  f1B = MFMA16(a11, b7, f1B);
        fsA = MFMA16(ah0, b7, fsA);  fsB = MFMA16(ah1, b7, fsB);
        aiA = MFMA16(ax0, b0, aiA);  aiB = MFMA16(ax1, b0, aiB);
        aoA = MFMA16(ax0, b1, aoA);  aoB = MFMA16(ax1, b1, aoB);
        auA = MFMA16(ax0, b2, auA);  auB = MFMA16(ax1, b2, auB);
        aiA = MFMA16(ah0, b3, aiA);  aiB = MFMA16(ah1, b3, aiB);
        aoA = MFMA16(ah0, b4, aoA);  aoB = MFMA16(ah1, b4, aoB);
        auA = MFMA16(ah0, b5, auA);  auB = MFMA16(ah1, b5, auB);
      }

      // ---- epilogue (both subtiles) ----
      #pragma unroll
      for (int st = 0; st < 2; ++st) {
        const f32x4& xf  = st ? xfB : xfA;
        const f32x4& f1h = st ? f1B : f1A;
        const f32x4& fs  = st ? fsB : fsA;
        const f32x4& ai  = st ? aiB : aiA;
        const f32x4& ao  = st ? aoB : aoA;
        const f32x4& au  = st ? auB : auA;
        const unsigned int* cpv = st ? cpB : cpA;
        const int drow0 = st ? drowB : drowA;
        float hv4[4], cv4[4];
        #pragma unroll
        for (int r = 0; r < 4; ++r) {
          const float i_ = sigm(ai[r] + bi_);
          const float u_ = tanh_f(au[r] + bu_);
          const float o_ = sigm(ao[r] + bo_);
          const float f1 = sigm(xf[r] + f1h[r] + bf_);
          const float f2 = sigm(xf[r] + fs[r] - f1h[r] + bf_);
          const float c1 = bf2f((unsigned short)(cpv[r] & 0xffffu));
          const float c2 = bf2f((unsigned short)(cpv[r] >> 16));
          const float c_ = i_ * u_ + f1 * c1 + f2 * c2;
          const float h_ = o_ * tanh_f(c_);
          cv4[r] = c_; hv4[r] = h_;
          const int j = drow0 + r;
          if (j < L)
            __builtin_nontemporal_store(h_, h_all + (size_t)(s + j) * 256 + colc);
        }
        if (root) {
          if (drow0 == 0) { out0[colc] = hv4[0]; out0[256 + colc] = cv4[0]; }
        } else {
          #pragma unroll
          for (int rp = 0; rp < 2; ++rp) {
            const int j0 = drow0 + rp * 2;
            if (j0 + 1 < L) {
              const int pp = j0 >> 1;
              hs_w [(size_t)pp * 256 + colc] = f2b(hv4[rp*2] + hv4[rp*2+1]);
              hbe_w[(size_t)pp * 256 + colc] = f2b(hv4[rp*2]);
              cp_w [(size_t)pp * 256 + colc] =
                  (unsigned int)f2b(cv4[rp*2]) | ((unsigned int)f2b(cv4[rp*2+1]) << 16);
            }
          }
        }
      }
    } else {
      // ---- leaf: i,o,u from x only, 2 subtiles sharing B ----
      f32x4 aiA = z4, aoA = z4, auA = z4, aiB = z4, aoB = z4, auB = z4;
      #pragma unroll 2
      for (int kc = 0; kc < 8; ++kc) {
        bf16x8 ax0 = *(const bf16x8*)(xr0 + kc * 32);
        bf16x8 ax1 = *(const bf16x8*)(xr1 + kc * 32);
        bf16x8 b0 = *(const bf16x8*)(LW + 0 * 4096 + kc * 512);
        bf16x8 b1 = *(const bf16x8*)(LW + 1 * 4096 + kc * 512);
        bf16x8 b2 = *(const bf16x8*)(LW + 2 * 4096 + kc * 512);
        aiA = MFMA16(ax0, b0, aiA);  aiB = MFMA16(ax1, b0, aiB);
        aoA = MFMA16(ax0, b1, aoA);  aoB = MFMA16(ax1, b1, aoB);
        auA = MFMA16(ax0, b2, auA);  auB = MFMA16(ax1, b2, auB);
      }
      #pragma unroll
      for (int st = 0; st < 2; ++st) {
        const f32x4& ai = st ? aiB : aiA;
        const f32x4& ao = st ? aoB : aoA;
        const f32x4& au = st ? auB : auA;
        const int drow0 = st ? drowB : drowA;
        float hv4[4], cv4[4];
        #pragma unroll
        for (int r = 0; r < 4; ++r) {
          const float i_ = sigm(ai[r] + bi_);
          const float u_ = tanh_f(au[r] + bu_);
          const float o_ = sigm(ao[r] + bo_);
          const float c_ = i_ * u_;
          const float h_ = o_ * tanh_f(c_);
          cv4[r] = c_; hv4[r] = h_;
          __builtin_nontemporal_store(h_, h_all + (size_t)(s + drow0 + r) * 256 + colc);
        }
        #pragma unroll
        for (int rp = 0; rp < 2; ++rp) {
          const int pp = (drow0 + rp * 2) >> 1;
          hs_w [(size_t)pp * 256 + colc] = f2b(hv4[rp*2] + hv4[rp*2+1]);
          hbe_w[(size_t)pp * 256 + colc] = f2b(hv4[rp*2]);
          cp_w [(size_t)pp * 256 + colc] =
              (unsigned int)f2b(cv4[rp*2]) | ((unsigned int)f2b(cv4[rp*2+1]) << 16);
        }
      }
    }
  }
}

extern "C" void kernel_launch(void* const* d_in, const int* in_sizes, int n_in,
                              void* d_out, int out_size, void* d_ws, size_t ws_size,
                              hipStream_t stream) {
  const float* inputs = (const float*)d_in[0];
  const float* Wioux  = (const float*)d_in[1];
  const float* bioux  = (const float*)d_in[2];
  const float* Wiouh  = (const float*)d_in[3];
  const float* Wfx    = (const float*)d_in[4];
  const float* bfx    = (const float*)d_in[5];
  const float* Wfh    = (const float*)d_in[6];
  const float* fb     = (const float*)d_in[7];

  const int N = in_sizes[0] / 256;       // 262143
  int depth = 0;
  while (((1 << depth) - 1) < N) ++depth;  // 18

  float* out   = (float*)d_out;
  float* h_all = out + 512;

  static bool attr_done = false;
  if (!attr_done) {
    hipFuncSetAttribute((const void*)level_k<0>,
                        hipFuncAttributeMaxDynamicSharedMemorySize, 8 * 8192);
    hipFuncSetAttribute((const void*)level_k<1>,
                        hipFuncAttributeMaxDynamicSharedMemorySize, 3 * 8192);
    attr_done = true;
  }

  // ws carve: parity-0 buffers (up to 65536 rows), parity-1 (32768), xb, wb
  char* p = (char*)d_ws;
  unsigned short* hs0  = (unsigned short*)p; p += (size_t)65536 * 256 * 2;
  unsigned short* hbe0 = (unsigned short*)p; p += (size_t)65536 * 256 * 2;
  unsigned int*   cp0  = (unsigned int*)p;   p += (size_t)65536 * 256 * 4;
  unsigned short* hs1  = (unsigned short*)p; p += (size_t)32768 * 256 * 2;
  unsigned short* hbe1 = (unsigned short*)p; p += (size_t)32768 * 256 * 2;
  unsigned int*   cp1  = (unsigned int*)p;   p += (size_t)32768 * 256 * 4;
  unsigned short* xb   = (unsigned short*)p; p += (size_t)N * 256 * 2;
  unsigned short* wb   = (unsigned short*)p;

  pack_w<<<2048, 256, 0, stream>>>(Wioux, Wiouh, Wfx, Wfh, wb);
  {
    const int n8 = (N * 256) / 8;
    conv_x<<<(n8 + 255) / 256, 256, 0, stream>>>(inputs, xb, n8);
  }

  for (int d = depth - 1; d >= 0; --d) {
    const int L = 1 << d;
    const int s = L - 1;
    const int T32 = (L + 31) / 32;
    // stripes: aim Tper ~ 8 (one tile per wave), cap 32 (XCD-aligned at >=8)
    int lg = 0; while ((1 << (lg + 1)) <= T32) ++lg;   // floor(log2 T32)
    int lns = lg - 3; if (lns < 0) lns = 0; if (lns > 5) lns = 5;
    const int rp_ = d & 1, wp_ = (d - 1) & 1;
    const unsigned short* hs_r  = rp_ ? hs1 : hs0;
    const unsigned short* hbe_r = rp_ ? hbe1 : hbe0;
    const unsigned int*   cp_r  = rp_ ? cp1 : cp0;
    unsigned short* hs_w  = wp_ ? hs1 : hs0;
    unsigned short* hbe_w = wp_ ? hbe1 : hbe0;
    unsigned int*   cp_w  = wp_ ? cp1 : cp0;
    if (d == depth - 1) {
      // leaf: 24KB LDS -> 4 blocks/CU; NS=64 -> grid 1024
      level_k<1><<<16 * 64, 512, 3 * 8192, stream>>>(
          xb, wb, bioux, bfx, fb, h_all,
          hs_r, hbe_r, cp_r, hs_w, hbe_w, cp_w, out, s, L, T32, 0, 6);
    } else {
      // interior: 64KB LDS -> 2 blocks/CU; grid = 16 cg * 2^lns
      level_k<0><<<16 << lns, 512, 8 * 8192, stream>>>(
          xb, wb, bioux, bfx, fb, h_all,
          hs_r, hbe_r, cp_r, hs_w, hbe_w, cp_w, out, s, L, T32, (d == 0) ? 1 : 0, lns);
    }
  }
}